// Round 9
// baseline (1713.164 us; speedup 1.0000x reference)
//
#include <hip/hip_runtime.h>
#include <hip/hip_cooperative_groups.h>
#include <math.h>

namespace cg = cooperative_groups;

// Problem constants (from reference)
constexpr int NN = 50000;     // nodes
constexpr int NE = 800000;    // edges
constexpr int H  = 128;       // hidden
constexpr int ED = 16;        // edge dim
constexpr int NL = 3;         // layers
constexpr int NG = 256;       // graphs
constexpr int NBINS = 50176;  // 196*256 >= NN
constexpr int TE = 128;       // edges per tile in edge kernel
constexpr int PREP_TOTAL = 294912 + NL*128*32 + NL*128*128 + NL*128*128 + 128*128; // 421888

typedef __attribute__((ext_vector_type(8))) short bf8;    // 8 bf16 in 4 VGPRs
typedef __attribute__((ext_vector_type(4))) float f32x4;  // MFMA accumulator

__device__ __forceinline__ unsigned short f2bf(float f) {
    unsigned u = __float_as_uint(f);
    unsigned r = (u + 0x7FFFu + ((u >> 16) & 1u)) >> 16;   // RNE
    return (unsigned short)r;
}
__device__ __forceinline__ float bf2f(unsigned short b) {
    return __uint_as_float(((unsigned)b) << 16);
}
__device__ __forceinline__ float fsig(float x) {
    float e = __expf(fminf(-x, 80.f));
    return 1.f / (1.f + e);
}
__device__ __forceinline__ float ftanh_(float x) {
    float e = __expf(fminf(-2.f * x, 80.f));
    return (1.f - e) / (1.f + e);
}

// ---------------------------------------------------------------------------
// weight prep, one flat index (layouts MFMA-B-ready: [n][k])
__device__ __forceinline__ void prep_one(int i,
        const float* __restrict__ wih, const float* __restrict__ whh,
        const float* __restrict__ w1, const float* __restrict__ w2,
        const float* __restrict__ lin_w,
        unsigned short* __restrict__ wgru, unsigned short* __restrict__ w1et,
        unsigned short* __restrict__ w2t, unsigned short* __restrict__ w1ht,
        unsigned short* __restrict__ winT) {
    if (i < 294912) {                     // gru weights, flat convert
        int m = i / 147456, rem = i % 147456;
        wgru[i] = f2bf((m == 0 ? wih : whh)[rem]);
        return;
    }
    i -= 294912;
    if (i < NL * 128 * 32) {              // w1 edge part, transposed, padded
        int l = i / 4096, rem = i % 4096;
        int n = rem >> 5, k = rem & 31;
        float v = (k < ED) ? w1[(size_t)l * 144 * 128 + (size_t)(128 + k) * 128 + n] : 0.f;
        w1et[i] = f2bf(v);
        return;
    }
    i -= NL * 128 * 32;
    if (i < NL * 128 * 128) {             // w2 transposed
        int l = i / 16384, rem = i % 16384;
        int n = rem >> 7, k = rem & 127;
        w2t[i] = f2bf(w2[(size_t)l * 16384 + (size_t)k * 128 + n]);
        return;
    }
    i -= NL * 128 * 128;
    if (i < NL * 128 * 128) {             // w1 node part, transposed
        int l = i / 16384, rem = i % 16384;
        int n = rem >> 7, k = rem & 127;
        w1ht[i] = f2bf(w1[(size_t)l * 144 * 128 + (size_t)k * 128 + n]);
        return;
    }
    i -= NL * 128 * 128;
    if (i < 128 * 128) {                  // lin_in_w transposed
        int n = i >> 7, k = i & 127;
        winT[i] = f2bf(lin_w[k * 128 + n]);
    }
}

// ---------------------------------------------------------------------------
// Cooperative: weight prep + counting sort of edges by dst + edge-data gather
// Grid size decided at launch via occupancy query (grid-stride phases).
__global__ __launch_bounds__(256) void k_coop(
        const float* __restrict__ wih, const float* __restrict__ whh,
        const float* __restrict__ w1, const float* __restrict__ w2,
        const float* __restrict__ lin_w,
        unsigned short* __restrict__ wgru, unsigned short* __restrict__ w1et,
        unsigned short* __restrict__ w2t, unsigned short* __restrict__ w1ht,
        unsigned short* __restrict__ winT,
        const int* __restrict__ ei, const float* __restrict__ ea,
        int* __restrict__ cnts, int* __restrict__ incl, int* __restrict__ bsum,
        int* __restrict__ cur, int* __restrict__ srcs, int* __restrict__ dsts,
        unsigned short* __restrict__ ea_bf) {
    cg::grid_group grid = cg::this_grid();
    const int t = threadIdx.x;
    const int gid = blockIdx.x * 256 + t;
    const int GT = gridDim.x * 256;
    __shared__ int s[256];

    // phase 0: zero counts + weight prep
    if (gid < NBINS) cnts[gid] = 0;
    for (int i = gid; i < PREP_TOTAL; i += GT)
        prep_one(i, wih, whh, w1, w2, lin_w, wgru, w1et, w2t, w1ht, winT);
    grid.sync();

    // phase 1: histogram over dst
    for (int e = gid; e < NE; e += GT) atomicAdd(&cnts[ei[NE + e]], 1);
    grid.sync();

    // phase 2: per-256-chunk inclusive scan (blocks 0..195)
    if (blockIdx.x < 196) {
        int v = cnts[gid];
        s[t] = v;
        __syncthreads();
        #pragma unroll
        for (int off = 1; off < 256; off <<= 1) {
            int x2 = (t >= off) ? s[t - off] : 0;
            __syncthreads();
            s[t] += x2;
            __syncthreads();
        }
        incl[gid] = s[t];
        if (t == 255) bsum[blockIdx.x] = s[255];
    }
    grid.sync();

    // phase 3: exclusive scan of block sums (block 0)
    if (blockIdx.x == 0) {
        int v = (t < 196) ? bsum[t] : 0;
        s[t] = v;
        __syncthreads();
        #pragma unroll
        for (int off = 1; off < 256; off <<= 1) {
            int x2 = (t >= off) ? s[t - off] : 0;
            __syncthreads();
            s[t] += x2;
            __syncthreads();
        }
        if (t < 196) bsum[t] = s[t] - v;
    }
    grid.sync();

    // phase 4: exclusive start offsets
    if (gid < NBINS) cur[gid] = incl[gid] - cnts[gid] + bsum[gid >> 8];
    grid.sync();

    // phase 5: scatter permutation (perm stored in srcs)
    for (int e = gid; e < NE; e += GT) {
        int d = ei[NE + e];
        int pos = atomicAdd(&cur[d], 1);
        srcs[pos] = e;
    }
    grid.sync();

    // phase 6: gather edge data into sorted order
    for (int i = gid; i < NE; i += GT) {
        int e = srcs[i];
        srcs[i] = ei[e];
        dsts[i] = ei[NE + e];
        const float4* sp = (const float4*)(ea + (size_t)e * ED);
        float4 v0 = sp[0], v1 = sp[1], v2 = sp[2], v3 = sp[3];
        union { uint4 u[2]; unsigned short sh[16]; } pk;
        pk.sh[0] = f2bf(v0.x); pk.sh[1] = f2bf(v0.y); pk.sh[2] = f2bf(v0.z); pk.sh[3] = f2bf(v0.w);
        pk.sh[4] = f2bf(v1.x); pk.sh[5] = f2bf(v1.y); pk.sh[6] = f2bf(v1.z); pk.sh[7] = f2bf(v1.w);
        pk.sh[8] = f2bf(v2.x); pk.sh[9] = f2bf(v2.y); pk.sh[10] = f2bf(v2.z); pk.sh[11] = f2bf(v2.w);
        pk.sh[12] = f2bf(v3.x); pk.sh[13] = f2bf(v3.y); pk.sh[14] = f2bf(v3.z); pk.sh[15] = f2bf(v3.w);
        uint4* d4 = (uint4*)(ea_bf + (size_t)i * 16);
        d4[0] = pk.u[0];
        d4[1] = pk.u[1];
    }
}

// ---------------------------------------------------------------------------
// Fused input projection: h = relu(x@Win+b); p_bf = bf16(h@W1h[0]); agg = 0.
__global__ __launch_bounds__(256) void k_inproj(const float* __restrict__ x,
                                                const unsigned short* __restrict__ winT,
                                                const float* __restrict__ bias,
                                                const unsigned short* __restrict__ w1h0,
                                                float* __restrict__ h,
                                                unsigned short* __restrict__ p_bf,
                                                float* __restrict__ agg) {
    __shared__ unsigned short As[32][136];
    const int t = threadIdx.x;
    const int w = t >> 6, lane = t & 63, l15 = lane & 15, q = lane >> 4;
    const int n0 = blockIdx.x * 32;

    bf8 bfr[2][4];
    #pragma unroll
    for (int nt = 0; nt < 2; ++nt) {
        int n = w * 32 + nt * 16 + l15;
        #pragma unroll
        for (int ks = 0; ks < 4; ++ks)
            bfr[nt][ks] = *(const bf8*)(winT + (size_t)n * 128 + ks * 32 + q * 8);
    }

    {
        int r = t >> 3, cs = (t & 7) * 16;
        int row = n0 + r;
        float4 v[4];
        if (row < NN) {
            const float4* src = (const float4*)(x + (size_t)row * H + cs);
            #pragma unroll
            for (int j = 0; j < 4; ++j) v[j] = src[j];
        } else {
            #pragma unroll
            for (int j = 0; j < 4; ++j) v[j] = make_float4(0.f, 0.f, 0.f, 0.f);
        }
        union { uint4 u[2]; unsigned short s[16]; } pk;
        #pragma unroll
        for (int j = 0; j < 4; ++j) {
            pk.s[j * 4 + 0] = f2bf(v[j].x); pk.s[j * 4 + 1] = f2bf(v[j].y);
            pk.s[j * 4 + 2] = f2bf(v[j].z); pk.s[j * 4 + 3] = f2bf(v[j].w);
        }
        *(uint4*)&As[r][cs] = pk.u[0];
        *(uint4*)&As[r][cs + 8] = pk.u[1];
    }
    __syncthreads();

    // zero agg rows owned by this block (layer-0 accumulator init)
    {
        int r = t >> 3, cs = (t & 7) * 16;
        int row = n0 + r;
        if (row < NN) {
            float4 z = make_float4(0.f, 0.f, 0.f, 0.f);
            float4* dz = (float4*)(agg + (size_t)row * H + cs);
            dz[0] = z; dz[1] = z; dz[2] = z; dz[3] = z;
        }
    }

    f32x4 acc[2][2];
    #pragma unroll
    for (int mt = 0; mt < 2; ++mt)
        #pragma unroll
        for (int nt = 0; nt < 2; ++nt) acc[mt][nt] = {0.f, 0.f, 0.f, 0.f};

    #pragma unroll
    for (int ks = 0; ks < 4; ++ks) {
        #pragma unroll
        for (int mt = 0; mt < 2; ++mt) {
            bf8 af = *(const bf8*)&As[mt * 16 + l15][ks * 32 + q * 8];
            acc[mt][0] = __builtin_amdgcn_mfma_f32_16x16x32_bf16(af, bfr[0][ks], acc[mt][0], 0, 0, 0);
            acc[mt][1] = __builtin_amdgcn_mfma_f32_16x16x32_bf16(af, bfr[1][ks], acc[mt][1], 0, 0, 0);
        }
    }
    __syncthreads();   // As reads done; reuse for h

    #pragma unroll
    for (int nt = 0; nt < 2; ++nt) {
        int col = w * 32 + nt * 16 + l15;
        float bv = bias[col];
        #pragma unroll
        for (int mt = 0; mt < 2; ++mt) {
            #pragma unroll
            for (int r = 0; r < 4; ++r) {
                int nl = mt * 16 + q * 4 + r;
                int node = n0 + nl;
                float v = fmaxf(acc[mt][nt][r] + bv, 0.f);
                if (node < NN) h[(size_t)node * H + col] = v;
                As[nl][col] = f2bf(v);
            }
        }
    }
    __syncthreads();

    // p = h @ W1h[0]
    bf8 pfr[2][4];
    #pragma unroll
    for (int nt = 0; nt < 2; ++nt) {
        int n = w * 32 + nt * 16 + l15;
        #pragma unroll
        for (int ks = 0; ks < 4; ++ks)
            pfr[nt][ks] = *(const bf8*)(w1h0 + (size_t)n * 128 + ks * 32 + q * 8);
    }
    f32x4 accp[2][2];
    #pragma unroll
    for (int mt = 0; mt < 2; ++mt)
        #pragma unroll
        for (int nt = 0; nt < 2; ++nt) accp[mt][nt] = {0.f, 0.f, 0.f, 0.f};
    #pragma unroll
    for (int ks = 0; ks < 4; ++ks) {
        #pragma unroll
        for (int mt = 0; mt < 2; ++mt) {
            bf8 af = *(const bf8*)&As[mt * 16 + l15][ks * 32 + q * 8];
            accp[mt][0] = __builtin_amdgcn_mfma_f32_16x16x32_bf16(af, pfr[0][ks], accp[mt][0], 0, 0, 0);
            accp[mt][1] = __builtin_amdgcn_mfma_f32_16x16x32_bf16(af, pfr[1][ks], accp[mt][1], 0, 0, 0);
        }
    }
    #pragma unroll
    for (int nt = 0; nt < 2; ++nt) {
        int col = w * 32 + nt * 16 + l15;
        #pragma unroll
        for (int mt = 0; mt < 2; ++mt) {
            #pragma unroll
            for (int r = 0; r < 4; ++r) {
                int node = n0 + mt * 16 + q * 4 + r;
                if (node < NN) p_bf[(size_t)node * H + col] = f2bf(accp[mt][nt][r]);
            }
        }
    }
}

// ---------------------------------------------------------------------------
// MFMA edge kernel, 128-edge tiles over dst-sorted pre-gathered edges.
// mt-halved loops cap VGPRs for 4 blocks/CU (measured L2 sweet spot).
__global__ __launch_bounds__(256, 4) void k_edge_mfma(
        const unsigned short* __restrict__ p,     // [NN][128] bf16
        const int* __restrict__ srcs,             // [NE] sorted
        const int* __restrict__ dsts,             // [NE] sorted
        const unsigned short* __restrict__ ea_bf, // [NE][16] bf16 sorted
        const unsigned short* __restrict__ w1et,  // [128][32] bf16
        const float* __restrict__ b1,
        const unsigned short* __restrict__ w2t,   // [128][128] bf16
        const float* __restrict__ b2,
        float* __restrict__ agg) {
    __shared__ unsigned short u_s[TE][136];   // 34.8 KB
    __shared__ int src_s[TE], dst_s[TE];

    const int t    = threadIdx.x;
    const int w    = t >> 6;
    const int lane = t & 63;
    const int l15  = lane & 15;
    const int q    = lane >> 4;

    bf8 w1f[2];
    bf8 w2f[2][4];
    float b1v[2], b2v[2];
    #pragma unroll
    for (int nt = 0; nt < 2; ++nt) {
        int n = w * 32 + nt * 16 + l15;
        w1f[nt] = *(const bf8*)(w1et + (size_t)n * 32 + q * 8);
        #pragma unroll
        for (int ks = 0; ks < 4; ++ks)
            w2f[nt][ks] = *(const bf8*)(w2t + (size_t)n * 128 + ks * 32 + q * 8);
        b1v[nt] = b1[n];
        b2v[nt] = b2[n];
    }

    const f32x4 zero = {0.f, 0.f, 0.f, 0.f};

    for (int base = blockIdx.x * TE; base < NE; base += gridDim.x * TE) {
        if (t < TE) src_s[t] = srcs[base + t];
        else        dst_s[t - TE] = dsts[base + t - TE];
        __syncthreads();   // S1

        // stage p rows (uint4, 16 lanes per row)
        {
            int row = t >> 4, seg = t & 15;
            #pragma unroll
            for (int it = 0; it < 8; ++it) {
                int rr = row + 16 * it;
                *(uint4*)&u_s[rr][seg * 8] =
                    *(const uint4*)(p + (size_t)src_s[rr] * H + seg * 8);
            }
        }

        // phase 1 + epilogue 1 in mt-halves (VGPR cap)
        #pragma unroll
        for (int half = 0; half < 2; ++half) {
            f32x4 acc1[4][2];
            #pragma unroll
            for (int m4 = 0; m4 < 4; ++m4) {
                int mt = half * 4 + m4;
                bf8 af = {0, 0, 0, 0, 0, 0, 0, 0};
                if (q < 2)
                    af = *(const bf8*)(ea_bf + (size_t)(base + mt * 16 + l15) * 16 + q * 8);
                acc1[m4][0] = __builtin_amdgcn_mfma_f32_16x16x32_bf16(af, w1f[0], zero, 0, 0, 0);
                acc1[m4][1] = __builtin_amdgcn_mfma_f32_16x16x32_bf16(af, w1f[1], zero, 0, 0, 0);
            }
            if (half == 0) __syncthreads();   // S2: p staged
            #pragma unroll
            for (int m4 = 0; m4 < 4; ++m4) {
                #pragma unroll
                for (int r = 0; r < 4; ++r) {
                    int er = (half * 4 + m4) * 16 + q * 4 + r;
                    #pragma unroll
                    for (int nt = 0; nt < 2; ++nt) {
                        int col = w * 32 + nt * 16 + l15;
                        float v = acc1[m4][nt][r] + bf2f(u_s[er][col]) + b1v[nt];
                        u_s[er][col] = f2bf(fmaxf(v, 0.f));
                    }
                }
            }
        }
        __syncthreads();   // S3: hid complete

        // phase 2 in mt-halves
        #pragma unroll
        for (int half = 0; half < 2; ++half) {
            f32x4 acc2[4][2];
            #pragma unroll
            for (int m4 = 0; m4 < 4; ++m4)
                #pragma unroll
                for (int nt = 0; nt < 2; ++nt) acc2[m4][nt] = zero;
            #pragma unroll
            for (int ks = 0; ks < 4; ++ks) {
                #pragma unroll
                for (int m4 = 0; m4 < 4; ++m4) {
                    int mt = half * 4 + m4;
                    bf8 af = *(const bf8*)&u_s[mt * 16 + l15][ks * 32 + q * 8];
                    acc2[m4][0] = __builtin_amdgcn_mfma_f32_16x16x32_bf16(af, w2f[0][ks], acc2[m4][0], 0, 0, 0);
                    acc2[m4][1] = __builtin_amdgcn_mfma_f32_16x16x32_bf16(af, w2f[1][ks], acc2[m4][1], 0, 0, 0);
                }
            }
            __syncthreads();   // S4: this half's hid reads done (all waves)
            #pragma unroll
            for (int m4 = 0; m4 < 4; ++m4) {
                #pragma unroll
                for (int r = 0; r < 4; ++r) {
                    int er = (half * 4 + m4) * 16 + q * 4 + r;
                    #pragma unroll
                    for (int nt = 0; nt < 2; ++nt) {
                        int col = w * 32 + nt * 16 + l15;
                        u_s[er][col] = f2bf(acc2[m4][nt][r] + b2v[nt]);
                    }
                }
            }
        }
        __syncthreads();   // S5: m ready

        // run-scan reduction over sorted dst: one atomic per (run, col)
        {
            int c = t & 127, hh = t >> 7;
            float* aggc = agg + c;
            float sum = 0.f;
            int prev = dst_s[hh * 64];
            #pragma unroll 4
            for (int i = 0; i < 64; ++i) {
                int e = hh * 64 + i;
                int d = dst_s[e];
                float v = bf2f(u_s[e][c]);
                if (d != prev) {
                    atomicAdd(aggc + (size_t)prev * H, sum);
                    sum = 0.f;
                    prev = d;
                }
                sum += v;
            }
            atomicAdd(aggc + (size_t)prev * H, sum);
        }
        __syncthreads();   // S6
    }
}

// ---------------------------------------------------------------------------
// MFMA GRU + BN + residual (+ fused next-layer p projection, agg re-zero,
// readout-buffer zero on last layer)
__global__ __launch_bounds__(256) void k_gru_mfma(float* __restrict__ agg,
                                                  float* __restrict__ h,
                                                  const unsigned short* __restrict__ wih,  // [384][128] bf16
                                                  const unsigned short* __restrict__ whh,  // [384][128] bf16
                                                  const float* __restrict__ bih,
                                                  const float* __restrict__ bhh,
                                                  const float* __restrict__ gamma,
                                                  const float* __restrict__ beta,
                                                  const float* __restrict__ mean,
                                                  const float* __restrict__ var,
                                                  const unsigned short* __restrict__ w1h_next, // or null
                                                  unsigned short* __restrict__ p_bf,
                                                  int* __restrict__ ro_z) {                   // or null
    __shared__ unsigned short ab[32][136];
    __shared__ unsigned short hb[32][136];
    __shared__ float hf[32][132];
    const int t = threadIdx.x;
    const int w = t >> 6, lane = t & 63, l15 = lane & 15, q = lane >> 4;
    const int n0 = blockIdx.x * 32;

    {
        int r = t >> 3, cs = (t & 7) * 16;
        int row = n0 + r;
        float4 va[4], vh[4];
        if (row < NN) {
            const float4* sa = (const float4*)(agg + (size_t)row * H + cs);
            const float4* sh = (const float4*)(h + (size_t)row * H + cs);
            #pragma unroll
            for (int j = 0; j < 4; ++j) { va[j] = sa[j]; vh[j] = sh[j]; }
        } else {
            #pragma unroll
            for (int j = 0; j < 4; ++j) {
                va[j] = make_float4(0.f, 0.f, 0.f, 0.f);
                vh[j] = va[j];
            }
        }
        union { uint4 u[2]; unsigned short s[16]; } pa, ph;
        #pragma unroll
        for (int j = 0; j < 4; ++j) {
            pa.s[j * 4 + 0] = f2bf(va[j].x); pa.s[j * 4 + 1] = f2bf(va[j].y);
            pa.s[j * 4 + 2] = f2bf(va[j].z); pa.s[j * 4 + 3] = f2bf(va[j].w);
            ph.s[j * 4 + 0] = f2bf(vh[j].x); ph.s[j * 4 + 1] = f2bf(vh[j].y);
            ph.s[j * 4 + 2] = f2bf(vh[j].z); ph.s[j * 4 + 3] = f2bf(vh[j].w);
            *(float4*)&hf[r][cs + j * 4] = vh[j];
        }
        *(uint4*)&ab[r][cs] = pa.u[0];  *(uint4*)&ab[r][cs + 8] = pa.u[1];
        *(uint4*)&hb[r][cs] = ph.u[0];  *(uint4*)&hb[r][cs + 8] = ph.u[1];
    }
    __syncthreads();

    // re-zero agg rows this block consumed (accumulator init for next layer)
    if (w1h_next != nullptr) {
        int r = t >> 3, cs = (t & 7) * 16;
        int row = n0 + r;
        if (row < NN) {
            float4 z = make_float4(0.f, 0.f, 0.f, 0.f);
            float4* dz = (float4*)(agg + (size_t)row * H + cs);
            dz[0] = z; dz[1] = z; dz[2] = z; dz[3] = z;
        }
    }
    // last layer: zero readout buffers (gsum|gmaxb|gcnt = 65792 contiguous words)
    if (ro_z != nullptr && blockIdx.x < 257) ro_z[blockIdx.x * 256 + t] = 0;

    f32x4 acc[2][2][3][2];
    #pragma unroll
    for (int mt = 0; mt < 2; ++mt)
        #pragma unroll
        for (int io = 0; io < 2; ++io)
            #pragma unroll
            for (int g = 0; g < 3; ++g)
                #pragma unroll
                for (int nt = 0; nt < 2; ++nt) acc[mt][io][g][nt] = {0.f, 0.f, 0.f, 0.f};

    #pragma unroll
    for (int ks = 0; ks < 4; ++ks) {
        bf8 a_a[2], a_h[2];
        #pragma unroll
        for (int mt = 0; mt < 2; ++mt) {
            a_a[mt] = *(const bf8*)&ab[mt * 16 + l15][ks * 32 + q * 8];
            a_h[mt] = *(const bf8*)&hb[mt * 16 + l15][ks * 32 + q * 8];
        }
        #pragma unroll
        for (int g = 0; g < 3; ++g) {
            #pragma unroll
            for (int nt = 0; nt < 2; ++nt) {
                int n = g * 128 + w * 32 + nt * 16 + l15;
                bf8 bi = *(const bf8*)(wih + (size_t)n * 128 + ks * 32 + q * 8);
                bf8 bh = *(const bf8*)(whh + (size_t)n * 128 + ks * 32 + q * 8);
                #pragma unroll
                for (int mt = 0; mt < 2; ++mt) {
                    acc[mt][0][g][nt] = __builtin_amdgcn_mfma_f32_16x16x32_bf16(a_a[mt], bi, acc[mt][0][g][nt], 0, 0, 0);
                    acc[mt][1][g][nt] = __builtin_amdgcn_mfma_f32_16x16x32_bf16(a_h[mt], bh, acc[mt][1][g][nt], 0, 0, 0);
                }
            }
        }
    }

    // epilogue -> out (registers), write h
    float rout[2][2][4];
    #pragma unroll
    for (int nt = 0; nt < 2; ++nt) {
        int col = w * 32 + nt * 16 + l15;
        float bir = bih[col], biz = bih[128 + col], bin = bih[256 + col];
        float bhr = bhh[col], bhz = bhh[128 + col], bhn = bhh[256 + col];
        float ga = gamma[col], be = beta[col], mu = mean[col];
        float iv = rsqrtf(var[col] + 1e-5f);
        #pragma unroll
        for (int mt = 0; mt < 2; ++mt) {
            #pragma unroll
            for (int r = 0; r < 4; ++r) {
                int nl = mt * 16 + q * 4 + r;
                int node = n0 + nl;
                float ir = acc[mt][0][0][nt][r] + bir;
                float iz = acc[mt][0][1][nt][r] + biz;
                float in = acc[mt][0][2][nt][r] + bin;
                float hr = acc[mt][1][0][nt][r] + bhr;
                float hz = acc[mt][1][1][nt][r] + bhz;
                float hn = acc[mt][1][2][nt][r] + bhn;
                float rg = fsig(ir + hr);
                float zg = fsig(iz + hz);
                float ng = ftanh_(in + rg * hn);
                float hv = hf[nl][col];
                float hnew = (1.f - zg) * ng + zg * hv;
                float bn = (hnew - mu) * iv * ga + be;
                float out = hv + bn;
                rout[nt][mt][r] = out;
                if (node < NN) h[(size_t)node * H + col] = out;
            }
        }
    }

    if (w1h_next != nullptr) {
        __syncthreads();   // all MFMA reads of hb done
        #pragma unroll
        for (int nt = 0; nt < 2; ++nt) {
            int col = w * 32 + nt * 16 + l15;
            #pragma unroll
            for (int mt = 0; mt < 2; ++mt)
                #pragma unroll
                for (int r = 0; r < 4; ++r)
                    hb[mt * 16 + q * 4 + r][col] = f2bf(rout[nt][mt][r]);
        }
        __syncthreads();

        // p = out @ W1h[next]
        f32x4 accp[2][2];
        #pragma unroll
        for (int mt = 0; mt < 2; ++mt)
            #pragma unroll
            for (int nt = 0; nt < 2; ++nt) accp[mt][nt] = {0.f, 0.f, 0.f, 0.f};
        #pragma unroll
        for (int ks = 0; ks < 4; ++ks) {
            bf8 pf0, pf1;
            {
                int n = w * 32 + l15;
                pf0 = *(const bf8*)(w1h_next + (size_t)n * 128 + ks * 32 + q * 8);
                pf1 = *(const bf8*)(w1h_next + (size_t)(n + 16) * 128 + ks * 32 + q * 8);
            }
            #pragma unroll
            for (int mt = 0; mt < 2; ++mt) {
                bf8 af = *(const bf8*)&hb[mt * 16 + l15][ks * 32 + q * 8];
                accp[mt][0] = __builtin_amdgcn_mfma_f32_16x16x32_bf16(af, pf0, accp[mt][0], 0, 0, 0);
                accp[mt][1] = __builtin_amdgcn_mfma_f32_16x16x32_bf16(af, pf1, accp[mt][1], 0, 0, 0);
            }
        }
        #pragma unroll
        for (int nt = 0; nt < 2; ++nt) {
            int col = w * 32 + nt * 16 + l15;
            #pragma unroll
            for (int mt = 0; mt < 2; ++mt) {
                #pragma unroll
                for (int r = 0; r < 4; ++r) {
                    int node = n0 + mt * 16 + q * 4 + r;
                    if (node < NN) p_bf[(size_t)node * H + col] = f2bf(accp[mt][nt][r]);
                }
            }
        }
    }
}

// ---------------------------------------------------------------------------
// readout
__device__ __forceinline__ unsigned fkey(float f) {
    unsigned b = __float_as_uint(f);
    return (b & 0x80000000u) ? ~b : (b | 0x80000000u);
}
__device__ __forceinline__ float funkey(unsigned k) {
    unsigned b = (k & 0x80000000u) ? (k & 0x7FFFFFFFu) : ~k;
    return __uint_as_float(b);
}

// run-scan readout over sorted batch: one atomic per (run, col)
__global__ __launch_bounds__(256) void k_ro_scan(const float* __restrict__ h,
                                                 const int* __restrict__ batch,
                                                 float* __restrict__ gsum,
                                                 unsigned* __restrict__ gmaxb,
                                                 float* __restrict__ gcnt) {
    __shared__ int bt_s[64];
    const int t = threadIdx.x;
    const int n0 = blockIdx.x * 64;   // grid 782
    if (t < 64) bt_s[t] = (n0 + t < NN) ? batch[n0 + t] : -1;
    __syncthreads();

    int c = t & 127, hh = t >> 7;
    float sum = 0.f, mx = -3.4e38f, cnt = 0.f;
    int prev = bt_s[hh * 32];
    #pragma unroll 4
    for (int i = 0; i < 32; ++i) {
        int e = hh * 32 + i;
        int g = bt_s[e];
        if (g != prev) {
            if (prev >= 0) {
                atomicAdd(&gsum[prev * H + c], sum);
                atomicMax(&gmaxb[prev * H + c], fkey(mx));
                if (c == 0) atomicAdd(&gcnt[prev], cnt);
            }
            sum = 0.f; mx = -3.4e38f; cnt = 0.f;
            prev = g;
        }
        if (g >= 0) {
            float v = h[(size_t)(n0 + e) * H + c];
            sum += v;
            mx = fmaxf(mx, v);
            cnt += 1.f;
        }
    }
    if (prev >= 0) {
        atomicAdd(&gsum[prev * H + c], sum);
        atomicMax(&gmaxb[prev * H + c], fkey(mx));
        if (c == 0) atomicAdd(&gcnt[prev], cnt);
    }
}

__global__ __launch_bounds__(128) void k_ro_final(const float* __restrict__ gsum,
                                                  const unsigned* __restrict__ gmaxb,
                                                  const float* __restrict__ gcnt,
                                                  const float* __restrict__ row,
                                                  const float* __restrict__ rob,
                                                  float* __restrict__ out) {
    __shared__ float cat[256];
    const int g = blockIdx.x, t = threadIdx.x;
    float cnt = gcnt[g];
    float inv = 1.f / fmaxf(cnt, 1.f);
    cat[t] = gsum[g * H + t] * inv;
    float mx = funkey(gmaxb[g * H + t]);
    cat[128 + t] = (cnt > 0.f) ? mx : 0.f;
    __syncthreads();
    float acc = rob[t];
    #pragma unroll 4
    for (int k = 0; k < 256; ++k) acc += cat[k] * row[k * H + t];
    out[g * H + t] = fmaxf(acc, 0.f);
}

// ---------------------------------------------------------------------------
extern "C" void kernel_launch(void* const* d_in, const int* in_sizes, int n_in,
                              void* d_out, int out_size, void* d_ws, size_t ws_size,
                              hipStream_t stream) {
    const float* x        = (const float*)d_in[0];
    const int*   ei       = (const int*)d_in[1];
    const float* ea       = (const float*)d_in[2];
    const int*   batch    = (const int*)d_in[3];
    const float* lin_in_w = (const float*)d_in[5];
    const float* lin_in_b = (const float*)d_in[6];
    const float* msg_w1   = (const float*)d_in[7];
    const float* msg_b1   = (const float*)d_in[8];
    const float* msg_w2   = (const float*)d_in[9];
    const float* msg_b2   = (const float*)d_in[10];
    const float* bn_gamma = (const float*)d_in[11];
    const float* bn_beta  = (const float*)d_in[12];
    const float* bn_mean  = (const float*)d_in[13];
    const float* bn_var   = (const float*)d_in[14];
    const float* gru_wih  = (const float*)d_in[15];
    const float* gru_whh  = (const float*)d_in[16];
    const float* gru_bih  = (const float*)d_in[17];
    const float* gru_bhh  = (const float*)d_in[18];
    const float* ro_w     = (const float*)d_in[19];
    const float* ro_b     = (const float*)d_in[20];

    float* ws = (float*)d_ws;
    float*          h     = ws;                                 // 6.4M
    float*          agg   = ws + 6400000;                       // 6.4M
    unsigned short* p_bf  = (unsigned short*)(ws + 12800000);   // 3.2M f
    float*          gsum  = ws + 16000000;                      // 32768
    unsigned*       gmaxb = (unsigned*)(ws + 16032768);         // 32768
    float*          gcnt  = ws + 16065536;                      // 256
    unsigned short* wgru  = (unsigned short*)(ws + 16065792);   // 147456 f
    unsigned short* w1et  = (unsigned short*)(ws + 16213248);   // 6144 f
    unsigned short* w2t   = (unsigned short*)(ws + 16219392);   // 24576 f
    unsigned short* w1ht  = (unsigned short*)(ws + 16243968);   // 24576 f
    unsigned short* winT  = (unsigned short*)(ws + 16268544);   // 8192 f
    int*            cnts  = (int*)(ws + 16276736);              // 50176
    int*            incl  = (int*)(ws + 16326912);              // 50176
    int*            cur   = (int*)(ws + 16377088);              // 50176
    int*            bsum  = (int*)(ws + 16427264);              // 256
    int*            srcs  = (int*)(ws + 16427520);              // 800000 (perm -> src_sorted)
    int*            dsts  = (int*)(ws + 17227520);              // 800000
    unsigned short* ea_bf = (unsigned short*)(ws + 18027520);   // 6.4M f
    // end: 24,427,520 floats (~97.7 MB)

    // cooperative: weight prep + counting sort by dst + edge-data gather.
    // Grid sized by the runtime's own cooperative-occupancy limit (R8 post-
    // mortem: hard-coded 2048 exceeded it and the launch aborted).
    {
        int maxB = 1;
        hipOccupancyMaxActiveBlocksPerMultiprocessor(&maxB, (const void*)k_coop, 256, 0);
        int coopGrid = maxB * 256;
        if (coopGrid > 2048) coopGrid = 2048;
        if (coopGrid < 256)  coopGrid = 256;   // 256 is R7-proven safe
        void* cargs[] = {
            (void*)&gru_wih, (void*)&gru_whh, (void*)&msg_w1, (void*)&msg_w2,
            (void*)&lin_in_w,
            (void*)&wgru, (void*)&w1et, (void*)&w2t, (void*)&w1ht, (void*)&winT,
            (void*)&ei, (void*)&ea,
            (void*)&cnts, (void*)&incl, (void*)&bsum, (void*)&cur,
            (void*)&srcs, (void*)&dsts, (void*)&ea_bf
        };
        hipLaunchCooperativeKernel((void*)k_coop, dim3(coopGrid), dim3(256), cargs, 0, stream);
    }

    // fused input projection: h = relu(x@Win+b), p_bf = h@W1h[0], agg = 0
    k_inproj<<<1563, 256, 0, stream>>>(x, winT, lin_in_b, w1ht, h, p_bf, agg);

    for (int l = 0; l < NL; ++l) {
        // edge MLP (MFMA) + sorted run-reduction into agg
        k_edge_mfma<<<1024, 256, 0, stream>>>(p_bf, srcs, dsts, ea_bf,
                                              w1et + (size_t)l * 4096, msg_b1 + l * 128,
                                              w2t + (size_t)l * 16384, msg_b2 + l * 128,
                                              agg);
        // GRU + BN + residual; fused next-layer p projection + agg/readout zero
        const unsigned short* w1h_next = (l + 1 < NL) ? (w1ht + (size_t)(l + 1) * 16384) : nullptr;
        int* ro_z = (l == NL - 1) ? (int*)gsum : nullptr;
        k_gru_mfma<<<1563, 256, 0, stream>>>(agg, h,
                                             wgru + (size_t)l * 49152,
                                             wgru + (size_t)(NL + l) * 49152,
                                             gru_bih + l * 384, gru_bhh + l * 384,
                                             bn_gamma + l * 128, bn_beta + l * 128,
                                             bn_mean + l * 128, bn_var + l * 128,
                                             w1h_next, p_bf, ro_z);
    }

    // readout
    k_ro_scan<<<782, 256, 0, stream>>>(h, batch, gsum, gmaxb, gcnt);
    k_ro_final<<<NG, 128, 0, stream>>>(gsum, gmaxb, gcnt, ro_w, ro_b, (float*)d_out);
}

// Round 10
// 803.350 us; speedup vs baseline: 2.1325x; 2.1325x over previous
//
#include <hip/hip_runtime.h>
#include <math.h>

// Problem constants (from reference)
constexpr int NN = 50000;     // nodes
constexpr int NE = 800000;    // edges
constexpr int H  = 128;       // hidden
constexpr int ED = 16;        // edge dim
constexpr int NL = 3;         // layers
constexpr int NG = 256;       // graphs
constexpr int NBINS = 50176;  // 196*256 >= NN
constexpr int TE = 128;       // edges per tile in edge kernel

typedef __attribute__((ext_vector_type(8))) short bf8;    // 8 bf16 in 4 VGPRs
typedef __attribute__((ext_vector_type(4))) float f32x4;  // MFMA accumulator

__device__ __forceinline__ unsigned short f2bf(float f) {
    unsigned u = __float_as_uint(f);
    unsigned r = (u + 0x7FFFu + ((u >> 16) & 1u)) >> 16;   // RNE
    return (unsigned short)r;
}
__device__ __forceinline__ float bf2f(unsigned short b) {
    return __uint_as_float(((unsigned)b) << 16);
}
__device__ __forceinline__ float fsig(float x) {
    float e = __expf(fminf(-x, 80.f));
    return 1.f / (1.f + e);
}
__device__ __forceinline__ float ftanh_(float x) {
    float e = __expf(fminf(-2.f * x, 80.f));
    return (1.f - e) / (1.f + e);
}

// ---------------------------------------------------------------------------
// counting sort of edges by dst (standalone kernels — stream ordering gives
// the dependencies; R9 showed grid.sync() at scale costs ~180 µs per barrier)
__global__ __launch_bounds__(256) void k_sort_zero(int* __restrict__ counts) {
    int i = blockIdx.x * 256 + threadIdx.x;   // grid 196
    counts[i] = 0;
}

__global__ __launch_bounds__(256) void k_hist(const int* __restrict__ ei,
                                              int* __restrict__ counts) {
    int e = blockIdx.x * 256 + threadIdx.x;
    if (e < NE) atomicAdd(&counts[ei[NE + e]], 1);
}

__global__ __launch_bounds__(256) void k_scan1(const int* __restrict__ counts,
                                               int* __restrict__ incl,
                                               int* __restrict__ bsum) {
    __shared__ int s[256];
    int t = threadIdx.x;
    int i = blockIdx.x * 256 + t;             // grid 196
    int v = counts[i];
    s[t] = v;
    __syncthreads();
    #pragma unroll
    for (int off = 1; off < 256; off <<= 1) {
        int x = (t >= off) ? s[t - off] : 0;
        __syncthreads();
        s[t] += x;
        __syncthreads();
    }
    incl[i] = s[t];
    if (t == 255) bsum[blockIdx.x] = s[255];
}

__global__ __launch_bounds__(256) void k_scan2(int* __restrict__ bsum) {
    __shared__ int s[256];
    int t = threadIdx.x;
    int v = (t < 196) ? bsum[t] : 0;
    s[t] = v;
    __syncthreads();
    #pragma unroll
    for (int off = 1; off < 256; off <<= 1) {
        int x = (t >= off) ? s[t - off] : 0;
        __syncthreads();
        s[t] += x;
        __syncthreads();
    }
    if (t < 196) bsum[t] = s[t] - v;          // exclusive
}

__global__ __launch_bounds__(256) void k_scan3(const int* __restrict__ counts,
                                               const int* __restrict__ incl,
                                               const int* __restrict__ bsum,
                                               int* __restrict__ cur) {
    int i = blockIdx.x * 256 + threadIdx.x;   // grid 196
    cur[i] = incl[i] - counts[i] + bsum[blockIdx.x];
}

__global__ __launch_bounds__(256) void k_scatter_perm(const int* __restrict__ ei,
                                                      int* __restrict__ cur,
                                                      int* __restrict__ perm) {
    int e = blockIdx.x * 256 + threadIdx.x;
    if (e < NE) {
        int d = ei[NE + e];
        int pos = atomicAdd(&cur[d], 1);
        perm[pos] = e;
    }
}

// gather per-edge data into sorted order
__global__ __launch_bounds__(256) void k_gather(const int* __restrict__ ei,
                                                const float* __restrict__ ea,
                                                int* __restrict__ perm,   // in: perm, out: src_sorted
                                                int* __restrict__ dsts,
                                                unsigned short* __restrict__ ea_bf) {
    int i = blockIdx.x * 256 + threadIdx.x;   // grid 3125
    if (i >= NE) return;
    int e = perm[i];
    perm[i] = ei[e];
    dsts[i] = ei[NE + e];
    const float4* sp = (const float4*)(ea + (size_t)e * ED);
    float4 v0 = sp[0], v1 = sp[1], v2 = sp[2], v3 = sp[3];
    union { uint4 u[2]; unsigned short sh[16]; } pk;
    pk.sh[0] = f2bf(v0.x); pk.sh[1] = f2bf(v0.y); pk.sh[2] = f2bf(v0.z); pk.sh[3] = f2bf(v0.w);
    pk.sh[4] = f2bf(v1.x); pk.sh[5] = f2bf(v1.y); pk.sh[6] = f2bf(v1.z); pk.sh[7] = f2bf(v1.w);
    pk.sh[8] = f2bf(v2.x); pk.sh[9] = f2bf(v2.y); pk.sh[10] = f2bf(v2.z); pk.sh[11] = f2bf(v2.w);
    pk.sh[12] = f2bf(v3.x); pk.sh[13] = f2bf(v3.y); pk.sh[14] = f2bf(v3.z); pk.sh[15] = f2bf(v3.w);
    uint4* d4 = (uint4*)(ea_bf + (size_t)i * 16);
    d4[0] = pk.u[0];
    d4[1] = pk.u[1];
}

// ---------------------------------------------------------------------------
// bf16 weight prep (all layouts MFMA-B-ready: [n][k])
__global__ __launch_bounds__(256) void k_prep(const float* __restrict__ wih,
                                              const float* __restrict__ whh,
                                              const float* __restrict__ w1,
                                              const float* __restrict__ w2,
                                              const float* __restrict__ lin_w,
                                              unsigned short* __restrict__ wgru,
                                              unsigned short* __restrict__ w1et,
                                              unsigned short* __restrict__ w2t,
                                              unsigned short* __restrict__ w1ht,
                                              unsigned short* __restrict__ winT) {
    int i = blockIdx.x * 256 + threadIdx.x;
    if (i < 294912) {                     // gru weights, flat convert
        int m = i / 147456, rem = i % 147456;
        wgru[i] = f2bf((m == 0 ? wih : whh)[rem]);
        return;
    }
    i -= 294912;
    if (i < NL * 128 * 32) {              // w1 edge part, transposed, padded
        int l = i / 4096, rem = i % 4096;
        int n = rem >> 5, k = rem & 31;
        float v = (k < ED) ? w1[(size_t)l * 144 * 128 + (size_t)(128 + k) * 128 + n] : 0.f;
        w1et[i] = f2bf(v);
        return;
    }
    i -= NL * 128 * 32;
    if (i < NL * 128 * 128) {             // w2 transposed
        int l = i / 16384, rem = i % 16384;
        int n = rem >> 7, k = rem & 127;
        w2t[i] = f2bf(w2[(size_t)l * 16384 + (size_t)k * 128 + n]);
        return;
    }
    i -= NL * 128 * 128;
    if (i < NL * 128 * 128) {             // w1 node part, transposed
        int l = i / 16384, rem = i % 16384;
        int n = rem >> 7, k = rem & 127;
        w1ht[i] = f2bf(w1[(size_t)l * 144 * 128 + (size_t)k * 128 + n]);
        return;
    }
    i -= NL * 128 * 128;
    if (i < 128 * 128) {                  // lin_in_w transposed
        int n = i >> 7, k = i & 127;
        winT[i] = f2bf(lin_w[k * 128 + n]);
    }
}

// ---------------------------------------------------------------------------
// Fused input projection: h = relu(x@Win+b); p_bf = bf16(h@W1h[0]); agg = 0.
__global__ __launch_bounds__(256) void k_inproj(const float* __restrict__ x,
                                                const unsigned short* __restrict__ winT,
                                                const float* __restrict__ bias,
                                                const unsigned short* __restrict__ w1h0,
                                                float* __restrict__ h,
                                                unsigned short* __restrict__ p_bf,
                                                float* __restrict__ agg) {
    __shared__ unsigned short As[32][136];
    const int t = threadIdx.x;
    const int w = t >> 6, lane = t & 63, l15 = lane & 15, q = lane >> 4;
    const int n0 = blockIdx.x * 32;

    bf8 bfr[2][4];
    #pragma unroll
    for (int nt = 0; nt < 2; ++nt) {
        int n = w * 32 + nt * 16 + l15;
        #pragma unroll
        for (int ks = 0; ks < 4; ++ks)
            bfr[nt][ks] = *(const bf8*)(winT + (size_t)n * 128 + ks * 32 + q * 8);
    }

    {
        int r = t >> 3, cs = (t & 7) * 16;
        int row = n0 + r;
        float4 v[4];
        if (row < NN) {
            const float4* src = (const float4*)(x + (size_t)row * H + cs);
            #pragma unroll
            for (int j = 0; j < 4; ++j) v[j] = src[j];
        } else {
            #pragma unroll
            for (int j = 0; j < 4; ++j) v[j] = make_float4(0.f, 0.f, 0.f, 0.f);
        }
        union { uint4 u[2]; unsigned short s[16]; } pk;
        #pragma unroll
        for (int j = 0; j < 4; ++j) {
            pk.s[j * 4 + 0] = f2bf(v[j].x); pk.s[j * 4 + 1] = f2bf(v[j].y);
            pk.s[j * 4 + 2] = f2bf(v[j].z); pk.s[j * 4 + 3] = f2bf(v[j].w);
        }
        *(uint4*)&As[r][cs] = pk.u[0];
        *(uint4*)&As[r][cs + 8] = pk.u[1];
    }
    __syncthreads();

    // zero agg rows owned by this block (layer-0 accumulator init)
    {
        int r = t >> 3, cs = (t & 7) * 16;
        int row = n0 + r;
        if (row < NN) {
            float4 z = make_float4(0.f, 0.f, 0.f, 0.f);
            float4* dz = (float4*)(agg + (size_t)row * H + cs);
            dz[0] = z; dz[1] = z; dz[2] = z; dz[3] = z;
        }
    }

    f32x4 acc[2][2];
    #pragma unroll
    for (int mt = 0; mt < 2; ++mt)
        #pragma unroll
        for (int nt = 0; nt < 2; ++nt) acc[mt][nt] = {0.f, 0.f, 0.f, 0.f};

    #pragma unroll
    for (int ks = 0; ks < 4; ++ks) {
        #pragma unroll
        for (int mt = 0; mt < 2; ++mt) {
            bf8 af = *(const bf8*)&As[mt * 16 + l15][ks * 32 + q * 8];
            acc[mt][0] = __builtin_amdgcn_mfma_f32_16x16x32_bf16(af, bfr[0][ks], acc[mt][0], 0, 0, 0);
            acc[mt][1] = __builtin_amdgcn_mfma_f32_16x16x32_bf16(af, bfr[1][ks], acc[mt][1], 0, 0, 0);
        }
    }
    __syncthreads();   // As reads done; reuse for h

    #pragma unroll
    for (int nt = 0; nt < 2; ++nt) {
        int col = w * 32 + nt * 16 + l15;
        float bv = bias[col];
        #pragma unroll
        for (int mt = 0; mt < 2; ++mt) {
            #pragma unroll
            for (int r = 0; r < 4; ++r) {
                int nl = mt * 16 + q * 4 + r;
                int node = n0 + nl;
                float v = fmaxf(acc[mt][nt][r] + bv, 0.f);
                if (node < NN) h[(size_t)node * H + col] = v;
                As[nl][col] = f2bf(v);
            }
        }
    }
    __syncthreads();

    // p = h @ W1h[0]
    bf8 pfr[2][4];
    #pragma unroll
    for (int nt = 0; nt < 2; ++nt) {
        int n = w * 32 + nt * 16 + l15;
        #pragma unroll
        for (int ks = 0; ks < 4; ++ks)
            pfr[nt][ks] = *(const bf8*)(w1h0 + (size_t)n * 128 + ks * 32 + q * 8);
    }
    f32x4 accp[2][2];
    #pragma unroll
    for (int mt = 0; mt < 2; ++mt)
        #pragma unroll
        for (int nt = 0; nt < 2; ++nt) accp[mt][nt] = {0.f, 0.f, 0.f, 0.f};
    #pragma unroll
    for (int ks = 0; ks < 4; ++ks) {
        #pragma unroll
        for (int mt = 0; mt < 2; ++mt) {
            bf8 af = *(const bf8*)&As[mt * 16 + l15][ks * 32 + q * 8];
            accp[mt][0] = __builtin_amdgcn_mfma_f32_16x16x32_bf16(af, pfr[0][ks], accp[mt][0], 0, 0, 0);
            accp[mt][1] = __builtin_amdgcn_mfma_f32_16x16x32_bf16(af, pfr[1][ks], accp[mt][1], 0, 0, 0);
        }
    }
    #pragma unroll
    for (int nt = 0; nt < 2; ++nt) {
        int col = w * 32 + nt * 16 + l15;
        #pragma unroll
        for (int mt = 0; mt < 2; ++mt) {
            #pragma unroll
            for (int r = 0; r < 4; ++r) {
                int node = n0 + mt * 16 + q * 4 + r;
                if (node < NN) p_bf[(size_t)node * H + col] = f2bf(accp[mt][nt][r]);
            }
        }
    }
}

// ---------------------------------------------------------------------------
// MFMA edge kernel, 128-edge tiles over dst-sorted pre-gathered edges.
// mt-halved loops cap VGPRs for 4 blocks/CU (measured L2 sweet spot).
__global__ __launch_bounds__(256, 4) void k_edge_mfma(
        const unsigned short* __restrict__ p,     // [NN][128] bf16
        const int* __restrict__ srcs,             // [NE] sorted
        const int* __restrict__ dsts,             // [NE] sorted
        const unsigned short* __restrict__ ea_bf, // [NE][16] bf16 sorted
        const unsigned short* __restrict__ w1et,  // [128][32] bf16
        const float* __restrict__ b1,
        const unsigned short* __restrict__ w2t,   // [128][128] bf16
        const float* __restrict__ b2,
        float* __restrict__ agg) {
    __shared__ unsigned short u_s[TE][136];   // 34.8 KB
    __shared__ int src_s[TE], dst_s[TE];

    const int t    = threadIdx.x;
    const int w    = t >> 6;
    const int lane = t & 63;
    const int l15  = lane & 15;
    const int q    = lane >> 4;

    bf8 w1f[2];
    bf8 w2f[2][4];
    float b1v[2], b2v[2];
    #pragma unroll
    for (int nt = 0; nt < 2; ++nt) {
        int n = w * 32 + nt * 16 + l15;
        w1f[nt] = *(const bf8*)(w1et + (size_t)n * 32 + q * 8);
        #pragma unroll
        for (int ks = 0; ks < 4; ++ks)
            w2f[nt][ks] = *(const bf8*)(w2t + (size_t)n * 128 + ks * 32 + q * 8);
        b1v[nt] = b1[n];
        b2v[nt] = b2[n];
    }

    const f32x4 zero = {0.f, 0.f, 0.f, 0.f};

    for (int base = blockIdx.x * TE; base < NE; base += gridDim.x * TE) {
        if (t < TE) src_s[t] = srcs[base + t];
        else        dst_s[t - TE] = dsts[base + t - TE];
        __syncthreads();   // S1

        // stage p rows (uint4, 16 lanes per row)
        {
            int row = t >> 4, seg = t & 15;
            #pragma unroll
            for (int it = 0; it < 8; ++it) {
                int rr = row + 16 * it;
                *(uint4*)&u_s[rr][seg * 8] =
                    *(const uint4*)(p + (size_t)src_s[rr] * H + seg * 8);
            }
        }

        // phase 1 + epilogue 1 in mt-halves (VGPR cap)
        #pragma unroll
        for (int half = 0; half < 2; ++half) {
            f32x4 acc1[4][2];
            #pragma unroll
            for (int m4 = 0; m4 < 4; ++m4) {
                int mt = half * 4 + m4;
                bf8 af = {0, 0, 0, 0, 0, 0, 0, 0};
                if (q < 2)
                    af = *(const bf8*)(ea_bf + (size_t)(base + mt * 16 + l15) * 16 + q * 8);
                acc1[m4][0] = __builtin_amdgcn_mfma_f32_16x16x32_bf16(af, w1f[0], zero, 0, 0, 0);
                acc1[m4][1] = __builtin_amdgcn_mfma_f32_16x16x32_bf16(af, w1f[1], zero, 0, 0, 0);
            }
            if (half == 0) __syncthreads();   // S2: p staged
            #pragma unroll
            for (int m4 = 0; m4 < 4; ++m4) {
                #pragma unroll
                for (int r = 0; r < 4; ++r) {
                    int er = (half * 4 + m4) * 16 + q * 4 + r;
                    #pragma unroll
                    for (int nt = 0; nt < 2; ++nt) {
                        int col = w * 32 + nt * 16 + l15;
                        float v = acc1[m4][nt][r] + bf2f(u_s[er][col]) + b1v[nt];
                        u_s[er][col] = f2bf(fmaxf(v, 0.f));
                    }
                }
            }
        }
        __syncthreads();   // S3: hid complete

        // phase 2 in mt-halves
        #pragma unroll
        for (int half = 0; half < 2; ++half) {
            f32x4 acc2[4][2];
            #pragma unroll
            for (int m4 = 0; m4 < 4; ++m4)
                #pragma unroll
                for (int nt = 0; nt < 2; ++nt) acc2[m4][nt] = zero;
            #pragma unroll
            for (int ks = 0; ks < 4; ++ks) {
                #pragma unroll
                for (int m4 = 0; m4 < 4; ++m4) {
                    int mt = half * 4 + m4;
                    bf8 af = *(const bf8*)&u_s[mt * 16 + l15][ks * 32 + q * 8];
                    acc2[m4][0] = __builtin_amdgcn_mfma_f32_16x16x32_bf16(af, w2f[0][ks], acc2[m4][0], 0, 0, 0);
                    acc2[m4][1] = __builtin_amdgcn_mfma_f32_16x16x32_bf16(af, w2f[1][ks], acc2[m4][1], 0, 0, 0);
                }
            }
            __syncthreads();   // S4: this half's hid reads done (all waves)
            #pragma unroll
            for (int m4 = 0; m4 < 4; ++m4) {
                #pragma unroll
                for (int r = 0; r < 4; ++r) {
                    int er = (half * 4 + m4) * 16 + q * 4 + r;
                    #pragma unroll
                    for (int nt = 0; nt < 2; ++nt) {
                        int col = w * 32 + nt * 16 + l15;
                        u_s[er][col] = f2bf(acc2[m4][nt][r] + b2v[nt]);
                    }
                }
            }
        }
        __syncthreads();   // S5: m ready

        // run-scan reduction over sorted dst: one atomic per (run, col)
        {
            int c = t & 127, hh = t >> 7;
            float* aggc = agg + c;
            float sum = 0.f;
            int prev = dst_s[hh * 64];
            #pragma unroll 4
            for (int i = 0; i < 64; ++i) {
                int e = hh * 64 + i;
                int d = dst_s[e];
                float v = bf2f(u_s[e][c]);
                if (d != prev) {
                    atomicAdd(aggc + (size_t)prev * H, sum);
                    sum = 0.f;
                    prev = d;
                }
                sum += v;
            }
            atomicAdd(aggc + (size_t)prev * H, sum);
        }
        __syncthreads();   // S6
    }
}

// ---------------------------------------------------------------------------
// MFMA GRU + BN + residual (+ fused next-layer p projection, agg re-zero,
// readout-buffer zero on last layer)
__global__ __launch_bounds__(256) void k_gru_mfma(float* __restrict__ agg,
                                                  float* __restrict__ h,
                                                  const unsigned short* __restrict__ wih,  // [384][128] bf16
                                                  const unsigned short* __restrict__ whh,  // [384][128] bf16
                                                  const float* __restrict__ bih,
                                                  const float* __restrict__ bhh,
                                                  const float* __restrict__ gamma,
                                                  const float* __restrict__ beta,
                                                  const float* __restrict__ mean,
                                                  const float* __restrict__ var,
                                                  const unsigned short* __restrict__ w1h_next, // or null
                                                  unsigned short* __restrict__ p_bf,
                                                  int* __restrict__ ro_z) {                   // or null
    __shared__ unsigned short ab[32][136];
    __shared__ unsigned short hb[32][136];
    __shared__ float hf[32][132];
    const int t = threadIdx.x;
    const int w = t >> 6, lane = t & 63, l15 = lane & 15, q = lane >> 4;
    const int n0 = blockIdx.x * 32;

    {
        int r = t >> 3, cs = (t & 7) * 16;
        int row = n0 + r;
        float4 va[4], vh[4];
        if (row < NN) {
            const float4* sa = (const float4*)(agg + (size_t)row * H + cs);
            const float4* sh = (const float4*)(h + (size_t)row * H + cs);
            #pragma unroll
            for (int j = 0; j < 4; ++j) { va[j] = sa[j]; vh[j] = sh[j]; }
        } else {
            #pragma unroll
            for (int j = 0; j < 4; ++j) {
                va[j] = make_float4(0.f, 0.f, 0.f, 0.f);
                vh[j] = va[j];
            }
        }
        union { uint4 u[2]; unsigned short s[16]; } pa, ph;
        #pragma unroll
        for (int j = 0; j < 4; ++j) {
            pa.s[j * 4 + 0] = f2bf(va[j].x); pa.s[j * 4 + 1] = f2bf(va[j].y);
            pa.s[j * 4 + 2] = f2bf(va[j].z); pa.s[j * 4 + 3] = f2bf(va[j].w);
            ph.s[j * 4 + 0] = f2bf(vh[j].x); ph.s[j * 4 + 1] = f2bf(vh[j].y);
            ph.s[j * 4 + 2] = f2bf(vh[j].z); ph.s[j * 4 + 3] = f2bf(vh[j].w);
            *(float4*)&hf[r][cs + j * 4] = vh[j];
        }
        *(uint4*)&ab[r][cs] = pa.u[0];  *(uint4*)&ab[r][cs + 8] = pa.u[1];
        *(uint4*)&hb[r][cs] = ph.u[0];  *(uint4*)&hb[r][cs + 8] = ph.u[1];
    }
    __syncthreads();

    // re-zero agg rows this block consumed (accumulator init for next layer)
    if (w1h_next != nullptr) {
        int r = t >> 3, cs = (t & 7) * 16;
        int row = n0 + r;
        if (row < NN) {
            float4 z = make_float4(0.f, 0.f, 0.f, 0.f);
            float4* dz = (float4*)(agg + (size_t)row * H + cs);
            dz[0] = z; dz[1] = z; dz[2] = z; dz[3] = z;
        }
    }
    // last layer: zero readout buffers (gsum|gmaxb|gcnt = 65792 contiguous words)
    if (ro_z != nullptr && blockIdx.x < 257) ro_z[blockIdx.x * 256 + t] = 0;

    f32x4 acc[2][2][3][2];
    #pragma unroll
    for (int mt = 0; mt < 2; ++mt)
        #pragma unroll
        for (int io = 0; io < 2; ++io)
            #pragma unroll
            for (int g = 0; g < 3; ++g)
                #pragma unroll
                for (int nt = 0; nt < 2; ++nt) acc[mt][io][g][nt] = {0.f, 0.f, 0.f, 0.f};

    #pragma unroll
    for (int ks = 0; ks < 4; ++ks) {
        bf8 a_a[2], a_h[2];
        #pragma unroll
        for (int mt = 0; mt < 2; ++mt) {
            a_a[mt] = *(const bf8*)&ab[mt * 16 + l15][ks * 32 + q * 8];
            a_h[mt] = *(const bf8*)&hb[mt * 16 + l15][ks * 32 + q * 8];
        }
        #pragma unroll
        for (int g = 0; g < 3; ++g) {
            #pragma unroll
            for (int nt = 0; nt < 2; ++nt) {
                int n = g * 128 + w * 32 + nt * 16 + l15;
                bf8 bi = *(const bf8*)(wih + (size_t)n * 128 + ks * 32 + q * 8);
                bf8 bh = *(const bf8*)(whh + (size_t)n * 128 + ks * 32 + q * 8);
                #pragma unroll
                for (int mt = 0; mt < 2; ++mt) {
                    acc[mt][0][g][nt] = __builtin_amdgcn_mfma_f32_16x16x32_bf16(a_a[mt], bi, acc[mt][0][g][nt], 0, 0, 0);
                    acc[mt][1][g][nt] = __builtin_amdgcn_mfma_f32_16x16x32_bf16(a_h[mt], bh, acc[mt][1][g][nt], 0, 0, 0);
                }
            }
        }
    }

    // epilogue -> out (registers), write h
    float rout[2][2][4];
    #pragma unroll
    for (int nt = 0; nt < 2; ++nt) {
        int col = w * 32 + nt * 16 + l15;
        float bir = bih[col], biz = bih[128 + col], bin = bih[256 + col];
        float bhr = bhh[col], bhz = bhh[128 + col], bhn = bhh[256 + col];
        float ga = gamma[col], be = beta[col], mu = mean[col];
        float iv = rsqrtf(var[col] + 1e-5f);
        #pragma unroll
        for (int mt = 0; mt < 2; ++mt) {
            #pragma unroll
            for (int r = 0; r < 4; ++r) {
                int nl = mt * 16 + q * 4 + r;
                int node = n0 + nl;
                float ir = acc[mt][0][0][nt][r] + bir;
                float iz = acc[mt][0][1][nt][r] + biz;
                float in = acc[mt][0][2][nt][r] + bin;
                float hr = acc[mt][1][0][nt][r] + bhr;
                float hz = acc[mt][1][1][nt][r] + bhz;
                float hn = acc[mt][1][2][nt][r] + bhn;
                float rg = fsig(ir + hr);
                float zg = fsig(iz + hz);
                float ng = ftanh_(in + rg * hn);
                float hv = hf[nl][col];
                float hnew = (1.f - zg) * ng + zg * hv;
                float bn = (hnew - mu) * iv * ga + be;
                float out = hv + bn;
                rout[nt][mt][r] = out;
                if (node < NN) h[(size_t)node * H + col] = out;
            }
        }
    }

    if (w1h_next != nullptr) {
        __syncthreads();   // all MFMA reads of hb done
        #pragma unroll
        for (int nt = 0; nt < 2; ++nt) {
            int col = w * 32 + nt * 16 + l15;
            #pragma unroll
            for (int mt = 0; mt < 2; ++mt)
                #pragma unroll
                for (int r = 0; r < 4; ++r)
                    hb[mt * 16 + q * 4 + r][col] = f2bf(rout[nt][mt][r]);
        }
        __syncthreads();

        // p = out @ W1h[next]
        f32x4 accp[2][2];
        #pragma unroll
        for (int mt = 0; mt < 2; ++mt)
            #pragma unroll
            for (int nt = 0; nt < 2; ++nt) accp[mt][nt] = {0.f, 0.f, 0.f, 0.f};
        #pragma unroll
        for (int ks = 0; ks < 4; ++ks) {
            bf8 pf0, pf1;
            {
                int n = w * 32 + l15;
                pf0 = *(const bf8*)(w1h_next + (size_t)n * 128 + ks * 32 + q * 8);
                pf1 = *(const bf8*)(w1h_next + (size_t)(n + 16) * 128 + ks * 32 + q * 8);
            }
            #pragma unroll
            for (int mt = 0; mt < 2; ++mt) {
                bf8 af = *(const bf8*)&hb[mt * 16 + l15][ks * 32 + q * 8];
                accp[mt][0] = __builtin_amdgcn_mfma_f32_16x16x32_bf16(af, pf0, accp[mt][0], 0, 0, 0);
                accp[mt][1] = __builtin_amdgcn_mfma_f32_16x16x32_bf16(af, pf1, accp[mt][1], 0, 0, 0);
            }
        }
        #pragma unroll
        for (int nt = 0; nt < 2; ++nt) {
            int col = w * 32 + nt * 16 + l15;
            #pragma unroll
            for (int mt = 0; mt < 2; ++mt) {
                #pragma unroll
                for (int r = 0; r < 4; ++r) {
                    int node = n0 + mt * 16 + q * 4 + r;
                    if (node < NN) p_bf[(size_t)node * H + col] = f2bf(accp[mt][nt][r]);
                }
            }
        }
    }
}

// ---------------------------------------------------------------------------
// readout
__device__ __forceinline__ unsigned fkey(float f) {
    unsigned b = __float_as_uint(f);
    return (b & 0x80000000u) ? ~b : (b | 0x80000000u);
}
__device__ __forceinline__ float funkey(unsigned k) {
    unsigned b = (k & 0x80000000u) ? (k & 0x7FFFFFFFu) : ~k;
    return __uint_as_float(b);
}

// run-scan readout over sorted batch: one atomic per (run, col)
__global__ __launch_bounds__(256) void k_ro_scan(const float* __restrict__ h,
                                                 const int* __restrict__ batch,
                                                 float* __restrict__ gsum,
                                                 unsigned* __restrict__ gmaxb,
                                                 float* __restrict__ gcnt) {
    __shared__ int bt_s[64];
    const int t = threadIdx.x;
    const int n0 = blockIdx.x * 64;   // grid 782
    if (t < 64) bt_s[t] = (n0 + t < NN) ? batch[n0 + t] : -1;
    __syncthreads();

    int c = t & 127, hh = t >> 7;
    float sum = 0.f, mx = -3.4e38f, cnt = 0.f;
    int prev = bt_s[hh * 32];
    #pragma unroll 4
    for (int i = 0; i < 32; ++i) {
        int e = hh * 32 + i;
        int g = bt_s[e];
        if (g != prev) {
            if (prev >= 0) {
                atomicAdd(&gsum[prev * H + c], sum);
                atomicMax(&gmaxb[prev * H + c], fkey(mx));
                if (c == 0) atomicAdd(&gcnt[prev], cnt);
            }
            sum = 0.f; mx = -3.4e38f; cnt = 0.f;
            prev = g;
        }
        if (g >= 0) {
            float v = h[(size_t)(n0 + e) * H + c];
            sum += v;
            mx = fmaxf(mx, v);
            cnt += 1.f;
        }
    }
    if (prev >= 0) {
        atomicAdd(&gsum[prev * H + c], sum);
        atomicMax(&gmaxb[prev * H + c], fkey(mx));
        if (c == 0) atomicAdd(&gcnt[prev], cnt);
    }
}

__global__ __launch_bounds__(128) void k_ro_final(const float* __restrict__ gsum,
                                                  const unsigned* __restrict__ gmaxb,
                                                  const float* __restrict__ gcnt,
                                                  const float* __restrict__ row,
                                                  const float* __restrict__ rob,
                                                  float* __restrict__ out) {
    __shared__ float cat[256];
    const int g = blockIdx.x, t = threadIdx.x;
    float cnt = gcnt[g];
    float inv = 1.f / fmaxf(cnt, 1.f);
    cat[t] = gsum[g * H + t] * inv;
    float mx = funkey(gmaxb[g * H + t]);
    cat[128 + t] = (cnt > 0.f) ? mx : 0.f;
    __syncthreads();
    float acc = rob[t];
    #pragma unroll 4
    for (int k = 0; k < 256; ++k) acc += cat[k] * row[k * H + t];
    out[g * H + t] = fmaxf(acc, 0.f);
}

// ---------------------------------------------------------------------------
extern "C" void kernel_launch(void* const* d_in, const int* in_sizes, int n_in,
                              void* d_out, int out_size, void* d_ws, size_t ws_size,
                              hipStream_t stream) {
    const float* x        = (const float*)d_in[0];
    const int*   ei       = (const int*)d_in[1];
    const float* ea       = (const float*)d_in[2];
    const int*   batch    = (const int*)d_in[3];
    const float* lin_in_w = (const float*)d_in[5];
    const float* lin_in_b = (const float*)d_in[6];
    const float* msg_w1   = (const float*)d_in[7];
    const float* msg_b1   = (const float*)d_in[8];
    const float* msg_w2   = (const float*)d_in[9];
    const float* msg_b2   = (const float*)d_in[10];
    const float* bn_gamma = (const float*)d_in[11];
    const float* bn_beta  = (const float*)d_in[12];
    const float* bn_mean  = (const float*)d_in[13];
    const float* bn_var   = (const float*)d_in[14];
    const float* gru_wih  = (const float*)d_in[15];
    const float* gru_whh  = (const float*)d_in[16];
    const float* gru_bih  = (const float*)d_in[17];
    const float* gru_bhh  = (const float*)d_in[18];
    const float* ro_w     = (const float*)d_in[19];
    const float* ro_b     = (const float*)d_in[20];

    float* ws = (float*)d_ws;
    float*          h     = ws;                                 // 6.4M
    float*          agg   = ws + 6400000;                       // 6.4M
    unsigned short* p_bf  = (unsigned short*)(ws + 12800000);   // 3.2M f
    float*          gsum  = ws + 16000000;                      // 32768
    unsigned*       gmaxb = (unsigned*)(ws + 16032768);         // 32768
    float*          gcnt  = ws + 16065536;                      // 256
    unsigned short* wgru  = (unsigned short*)(ws + 16065792);   // 147456 f
    unsigned short* w1et  = (unsigned short*)(ws + 16213248);   // 6144 f
    unsigned short* w2t   = (unsigned short*)(ws + 16219392);   // 24576 f
    unsigned short* w1ht  = (unsigned short*)(ws + 16243968);   // 24576 f
    unsigned short* winT  = (unsigned short*)(ws + 16268544);   // 8192 f
    int*            cnts  = (int*)(ws + 16276736);              // 50176
    int*            incl  = (int*)(ws + 16326912);              // 50176
    int*            cur   = (int*)(ws + 16377088);              // 50176
    int*            bsum  = (int*)(ws + 16427264);              // 256
    int*            srcs  = (int*)(ws + 16427520);              // 800000 (perm -> src_sorted)
    int*            dsts  = (int*)(ws + 17227520);              // 800000
    unsigned short* ea_bf = (unsigned short*)(ws + 18027520);   // 6.4M f
    // end: 24,427,520 floats (~97.7 MB)

    // weight prep (bf16, B-layout) + counting sort of edges by dst + gather.
    // Standalone kernels: stream ordering provides dependencies at HW speed
    // (R9: grid.sync() at 2048 blocks cost ~180 µs per barrier — coop dead end).
    k_prep<<<1648, 256, 0, stream>>>(gru_wih, gru_whh, msg_w1, msg_w2, lin_in_w,
                                     wgru, w1et, w2t, w1ht, winT);
    k_sort_zero<<<196, 256, 0, stream>>>(cnts);
    k_hist<<<3125, 256, 0, stream>>>(ei, cnts);
    k_scan1<<<196, 256, 0, stream>>>(cnts, incl, bsum);
    k_scan2<<<1, 256, 0, stream>>>(bsum);
    k_scan3<<<196, 256, 0, stream>>>(cnts, incl, bsum, cur);
    k_scatter_perm<<<3125, 256, 0, stream>>>(ei, cur, srcs);
    k_gather<<<3125, 256, 0, stream>>>(ei, ea, srcs, dsts, ea_bf);

    // fused input projection: h = relu(x@Win+b), p_bf = h@W1h[0], agg = 0
    k_inproj<<<1563, 256, 0, stream>>>(x, winT, lin_in_b, w1ht, h, p_bf, agg);

    for (int l = 0; l < NL; ++l) {
        // edge MLP (MFMA) + sorted run-reduction into agg
        k_edge_mfma<<<1024, 256, 0, stream>>>(p_bf, srcs, dsts, ea_bf,
                                              w1et + (size_t)l * 4096, msg_b1 + l * 128,
                                              w2t + (size_t)l * 16384, msg_b2 + l * 128,
                                              agg);
        // GRU + BN + residual; fused next-layer p projection + agg/readout zero
        const unsigned short* w1h_next = (l + 1 < NL) ? (w1ht + (size_t)(l + 1) * 16384) : nullptr;
        int* ro_z = (l == NL - 1) ? (int*)gsum : nullptr;
        k_gru_mfma<<<1563, 256, 0, stream>>>(agg, h,
                                             wgru + (size_t)l * 49152,
                                             wgru + (size_t)(NL + l) * 49152,
                                             gru_bih + l * 384, gru_bhh + l * 384,
                                             bn_gamma + l * 128, bn_beta + l * 128,
                                             bn_mean + l * 128, bn_var + l * 128,
                                             w1h_next, p_bf, ro_z);
    }

    // readout
    k_ro_scan<<<782, 256, 0, stream>>>(h, batch, gsum, gmaxb, gcnt);
    k_ro_final<<<NG, 128, 0, stream>>>(gsum, gmaxb, gcnt, ro_w, ro_b, (float*)d_out);
}